// Round 8
// baseline (361.802 us; speedup 1.0000x reference)
//
#include <hip/hip_runtime.h>
#include <math.h>

constexpr int NP = 100000, NA = 50000, NS = 5000;
constexpr int EPA = 600000, EAP = 600000, EPS = 200000, ESP = 200000;
// concatenated relation order: pa | ps | ap | sp   (dst spaces: A | S | P | P)
constexpr int ETOT = EPA + EPS + EAP + ESP;            // 1.6M
constexpr int NT   = NA + NS + NP + NP;                // 255000 global dst rows
constexpr int OFF_PS = EPA, OFF_AP = EPA + EPS, OFF_SP = EPA + EPS + EAP;
constexpr int ROW_PS = NA, ROW_AP = NA + NS, ROW_SP = NA + NS + NP;

constexpr int NB_FOLD = 2;
constexpr int NB_PACK = (256*128)/256;          // 128
constexpr int NB_HIST = (ETOT + 1023)/1024;     // 1563 (4 edges/thread)
constexpr int HIST_BASE = NB_FOLD + NB_PACK;    // 130
constexpr int NB_ENC  = (NP + 63)/64;           // 1563
constexpr int NB_FILL = (ETOT + 1023)/1024;     // 1563

typedef short s16x8 __attribute__((ext_vector_type(8)));
typedef float f32x4 __attribute__((ext_vector_type(4)));
typedef unsigned short u16;

__device__ __forceinline__ float gelu_f(float x) {
  float x3 = x*x*x;
  return 0.5f*x*(1.0f + tanhf(0.7978845608028654f*(x + 0.044715f*x3)));
}
__device__ __forceinline__ u16 f2bf(float f) {
  unsigned u = __float_as_uint(f);
  u += 0x7fffu + ((u >> 16) & 1u);     // RNE
  return (u16)(u >> 16);
}
__device__ __forceinline__ float bf2f(u16 s) {
  return __uint_as_float((unsigned)s << 16);
}

// ================= K0: fold | pack | rank-recording histogram =================
// b<2: fold (WFi = w0 @ (w1 @ out_w), interleaved [128][32])
// b<130: pack encoder W into MFMA fragment order
// else: histogram with bin = histblk&7; rank[e] = old count (u16)
__global__ __launch_bounds__(256) void prep(
    const float* __restrict__ w0_pa, const float* __restrict__ w1_ap,
    const float* __restrict__ w0_ps, const float* __restrict__ w1_sp,
    const float* __restrict__ out_w, float* __restrict__ WFi,
    const float* __restrict__ ewp, u16* __restrict__ wpk,
    const int* __restrict__ pa_d, const int* __restrict__ ps_d,
    const int* __restrict__ ap_d, const int* __restrict__ sp_d,
    int* __restrict__ h, u16* __restrict__ rank16)
{
  __shared__ float Wst[64*132];
  __shared__ float OW[128*16];
  __shared__ float U[128*16];
  const int b = blockIdx.x, tid = threadIdx.x;

  if (b >= HIST_BASE) {
    const int hblk = b - HIST_BASE;
    const int e = hblk*1024 + tid*4;
    if (e >= ETOT) return;
    const int* dsts; int off;
    if (e < OFF_PS)      { dsts = pa_d;          off = 0; }
    else if (e < OFF_AP) { dsts = ps_d - OFF_PS; off = ROW_PS; }
    else if (e < OFF_SP) { dsts = ap_d - OFF_AP; off = ROW_AP; }
    else                 { dsts = sp_d - OFF_SP; off = ROW_SP; }
    int4 d4 = *(const int4*)(dsts + e);
    int* hb = h + (hblk & 7)*NT + off;
    unsigned p0 = (unsigned)atomicAdd(&hb[d4.x], 1);
    unsigned p1 = (unsigned)atomicAdd(&hb[d4.y], 1);
    unsigned p2 = (unsigned)atomicAdd(&hb[d4.z], 1);
    unsigned p3 = (unsigned)atomicAdd(&hb[d4.w], 1);
    uint2 rr;
    rr.x = (p0 & 0xffffu) | (p1 << 16);
    rr.y = (p2 & 0xffffu) | (p3 << 16);
    *(uint2*)(rank16 + e) = rr;
    return;
  }
  if (b >= NB_FOLD) {
    int o = (b - NB_FOLD)*256 + tid;
    int bb = o & 7;
    int l  = (o >> 3) & 63;
    int cf = (o >> 9) & 7;
    int ks = o >> 12;
    wpk[o] = f2bf(ewp[(ks*32 + (l>>4)*8 + bb)*128 + cf*16 + (l & 15)]);
    return;
  }

  // ---- fold role ----
  const float* w0 = (b == 0) ? w0_pa : w0_ps;
  const float* w1 = (b == 0) ? w1_ap : w1_sp;
  for (int i = tid; i < 512; i += 256) ((float4*)OW)[i] = ((const float4*)out_w)[i];
  for (int half = 0; half < 2; ++half) {
    __syncthreads();
    for (int i = tid; i < 64*32; i += 256) {
      int row = i >> 5, q = i & 31;
      float4 v = ((const float4*)(w1 + (size_t)(half*64 + row)*128))[q];
      *(float4*)&Wst[row*132 + q*4] = v;
    }
    __syncthreads();
    #pragma unroll
    for (int i = 0; i < 4; ++i) {
      int idx = tid + 256*i;
      int r = idx >> 4, c = idx & 15;
      float acc = 0.f;
      #pragma unroll 8
      for (int k = 0; k < 128; ++k) acc = fmaf(Wst[r*132+k], OW[k*16+c], acc);
      U[(half*64 + r)*16 + c] = acc;
    }
  }
  for (int half = 0; half < 2; ++half) {
    __syncthreads();
    for (int i = tid; i < 64*32; i += 256) {
      int row = i >> 5, q = i & 31;
      float4 v = ((const float4*)(w0 + (size_t)(half*64 + row)*128))[q];
      *(float4*)&Wst[row*132 + q*4] = v;
    }
    __syncthreads();
    #pragma unroll
    for (int i = 0; i < 4; ++i) {
      int idx = tid + 256*i;
      int r = idx >> 4, c = idx & 15;
      float acc = 0.f;
      #pragma unroll 8
      for (int k = 0; k < 128; ++k) acc = fmaf(Wst[r*132+k], U[k*16+c], acc);
      WFi[(half*64 + r)*32 + b*16 + c] = acc;
    }
  }
}

// ================= scans (rows = sum over 8 bins) =================
__global__ __launch_bounds__(256) void scan_partial(const int* __restrict__ h, int n,
                                                    int* __restrict__ part) {
  __shared__ int red[4];
  int base = blockIdx.x*4096;
  int sum = 0;
  for (int i = threadIdx.x; i < 4096; i += 256) {
    int idx = base + i;
    if (idx < n) {
      #pragma unroll
      for (int bb = 0; bb < 8; ++bb) sum += h[bb*NT + idx];
    }
  }
  #pragma unroll
  for (int off = 32; off; off >>= 1) sum += __shfl_down(sum, off, 64);
  if ((threadIdx.x & 63) == 0) red[threadIdx.x >> 6] = sum;
  __syncthreads();
  if (threadIdx.x == 0) part[blockIdx.x] = red[0]+red[1]+red[2]+red[3];
}

// exclusive scan -> rp[0..n]; also rpo[b][row] = rp[row] + prefix over bins
__global__ __launch_bounds__(256) void scan_chunk(const int* __restrict__ h, int n,
    const int* __restrict__ part, int* __restrict__ out, int* __restrict__ rpo)
{
  int off0 = 0;
  for (int i = 0; i < (int)blockIdx.x; ++i) off0 += part[i];
  const int base = blockIdx.x*4096 + threadIdx.x*16;
  int loc[16]; int s = 0;
  #pragma unroll
  for (int j = 0; j < 16; ++j) {
    int idx = base + j;
    int v = 0;
    if (idx < n) {
      #pragma unroll
      for (int bb = 0; bb < 8; ++bb) v += h[bb*NT + idx];
    }
    loc[j] = s; s += v;
  }
  __shared__ int ts[256];
  ts[threadIdx.x] = s; __syncthreads();
  for (int off = 1; off < 256; off <<= 1) {
    int t = (threadIdx.x >= off) ? ts[threadIdx.x - off] : 0;
    __syncthreads();
    ts[threadIdx.x] += t;
    __syncthreads();
  }
  int excl = off0 + ts[threadIdx.x] - s;
  #pragma unroll
  for (int j = 0; j < 16; ++j) {
    int idx = base + j;
    if (idx < n) {
      int rp = excl + loc[j];
      out[idx] = rp;
      int run = rp, tot = 0;
      #pragma unroll
      for (int bb = 0; bb < 8; ++bb) {
        rpo[bb*NT + idx] = run;
        int hv = h[bb*NT + idx];
        run += hv; tot += hv;
      }
      if (idx == n-1) out[n] = rp + tot;
    }
  }
}

// ================= K3: fused encoder || CSR fill (atomic-free fill) =================
// b odd: encoder block; b even: fill block.
__global__ __launch_bounds__(256) void enc_fill(
    const float* __restrict__ A, const u16* __restrict__ Wp,
    const float* __restrict__ bias, const float* __restrict__ WFi,
    float* __restrict__ YZ,
    const int* __restrict__ pa_s, const int* __restrict__ pa_d,
    const int* __restrict__ ps_s, const int* __restrict__ ps_d,
    const int* __restrict__ ap_s, const int* __restrict__ ap_d,
    const int* __restrict__ sp_s, const int* __restrict__ sp_d,
    const int* __restrict__ rpo, const u16* __restrict__ rank16,
    int* __restrict__ ci)
{
  __shared__ u16 hl[64][132];
  const int b = blockIdx.x;
  const int tid = threadIdx.x;

  if (!(b & 1)) {
    // ---- fill role: slot = rpo[bin][row] + rank; no atomics ----
    const int fb = b >> 1;
    const int e = fb*1024 + tid*4;
    if (e >= ETOT) return;
    const int *srcs, *dsts; int off;
    if (e < OFF_PS)      { srcs = pa_s;          dsts = pa_d;          off = 0; }
    else if (e < OFF_AP) { srcs = ps_s - OFF_PS; dsts = ps_d - OFF_PS; off = ROW_PS; }
    else if (e < OFF_SP) { srcs = ap_s - OFF_AP; dsts = ap_d - OFF_AP; off = ROW_AP; }
    else                 { srcs = sp_s - OFF_SP; dsts = sp_d - OFF_SP; off = ROW_SP; }
    int4 s4 = *(const int4*)(srcs + e);
    int4 d4 = *(const int4*)(dsts + e);
    uint2 rr = *(const uint2*)(rank16 + e);
    const int* rpoB = rpo + ((e >> 10) & 7)*NT + off;   // same bin formula as hist
    ci[rpoB[d4.x] + (int)(rr.x & 0xffffu)] = s4.x;
    ci[rpoB[d4.y] + (int)(rr.x >> 16)]     = s4.y;
    ci[rpoB[d4.z] + (int)(rr.y & 0xffffu)] = s4.z;
    ci[rpoB[d4.w] + (int)(rr.y >> 16)]     = s4.w;
    return;
  }

  // ---- encoder role: yz = gelu(x_p @ Wenc + b) @ [Wao|Wso] ----
  const int eb = b >> 1;
  const int lane = tid & 63, wv = tid >> 6;
  const int rowbase = eb*64 + wv*16;
  const int m  = lane & 15;
  const int kq = lane >> 4;

  f32x4 acc[8];
  #pragma unroll
  for (int j = 0; j < 8; ++j) acc[j] = (f32x4){0.f,0.f,0.f,0.f};

  const int r0 = rowbase + m;
  const bool v0 = r0 < NP;
  const float* Arow = A + (size_t)r0*256 + kq*8;

  #pragma unroll
  for (int ks = 0; ks < 8; ++ks) {
    s16x8 a0 = {0,0,0,0,0,0,0,0};
    if (v0) {
      float4 f = *(const float4*)(Arow + ks*32);
      float4 g = *(const float4*)(Arow + ks*32 + 4);
      a0[0]=(short)f2bf(f.x); a0[1]=(short)f2bf(f.y); a0[2]=(short)f2bf(f.z); a0[3]=(short)f2bf(f.w);
      a0[4]=(short)f2bf(g.x); a0[5]=(short)f2bf(g.y); a0[6]=(short)f2bf(g.z); a0[7]=(short)f2bf(g.w);
    }
    const s16x8* Wf = (const s16x8*)Wp + (size_t)ks*512 + lane;
    #pragma unroll
    for (int cf = 0; cf < 8; ++cf)
      acc[cf] = __builtin_amdgcn_mfma_f32_16x16x32_bf16(a0, Wf[cf*64], acc[cf], 0, 0, 0);
  }

  // h -> LDS (bf16); D layout: col = lane&15, row-in-tile = kq*4 + r
  const int rlb = wv*16 + kq*4;
  #pragma unroll
  for (int cf = 0; cf < 8; ++cf) {
    const int col = cf*16 + m;
    const float bcol = bias[col];
    #pragma unroll
    for (int r = 0; r < 4; ++r)
      hl[rlb + r][col] = f2bf(gelu_f(acc[cf][r] + bcol));
  }
  __syncthreads();

  // yz[row][0..31] = h[row] @ WFi ; WFi read from global (16KB, L1/L2-hot)
  const int r = tid >> 2;
  const int cg = (tid & 3) * 8;
  const int grow = eb*64 + r;
  if (grow >= NP) return;
  float s[8];
  #pragma unroll
  for (int j = 0; j < 8; ++j) s[j] = 0.f;
  #pragma unroll 4
  for (int k = 0; k < 128; ++k) {
    const float hv = bf2f(hl[r][k]);
    const float* wk = WFi + k*32 + cg;
    #pragma unroll
    for (int j = 0; j < 8; ++j) s[j] = fmaf(hv, wk[j], s[j]);
  }
  float* O = YZ + (size_t)grow*32 + cg;
  *(float4*)(O)   = make_float4(s[0], s[1], s[2], s[3]);
  *(float4*)(O+4) = make_float4(s[4], s[5], s[6], s[7]);
}

// ================= 16-wide gathers =================
__global__ __launch_bounds__(256) void gather16(const float* __restrict__ yz,
    const int* __restrict__ rp, const int* __restrict__ ci,
    float* __restrict__ m16, int n)
{
  int t = blockIdx.x*256 + threadIdx.x;
  int row = t >> 4, lane = t & 15;
  if (row >= n) return;
  int beg = rp[row], end = rp[row+1];
  int off = (row < NA ? 0 : 16) + lane;
  float a = 0.f, b = 0.f;
  int e = beg;
  for (; e + 1 < end; e += 2) {
    a += yz[(size_t)ci[e]  *32 + off];
    b += yz[(size_t)ci[e+1]*32 + off];
  }
  if (e < end) a += yz[(size_t)ci[e]*32 + off];
  int d = end - beg;
  m16[(size_t)row*16 + lane] = (a + b) / (float)(d > 0 ? d : 1);
}

__global__ __launch_bounds__(256) void gather2_16(
    const float* __restrict__ f1, const int* __restrict__ rp1,
    const float* __restrict__ f2, const int* __restrict__ rp2,
    const int* __restrict__ ci, const float* __restrict__ ob,
    float* __restrict__ O, int n)
{
  int t = blockIdx.x*256 + threadIdx.x;
  int row = t >> 4, lane = t & 15;
  if (row >= n) return;

  float s1 = 0.f, s1b = 0.f;
  {
    int beg = rp1[row], end = rp1[row+1];
    int e = beg;
    for (; e + 1 < end; e += 2) {
      s1  += f1[(size_t)ci[e]  *16 + lane];
      s1b += f1[(size_t)ci[e+1]*16 + lane];
    }
    if (e < end) s1 += f1[(size_t)ci[e]*16 + lane];
    int d = end - beg;
    s1 = (s1 + s1b) / (float)(d > 0 ? d : 1);
  }
  float s2 = 0.f, s2b = 0.f;
  {
    int beg = rp2[row], end = rp2[row+1];
    int e = beg;
    for (; e + 1 < end; e += 2) {
      s2  += f2[(size_t)ci[e]  *16 + lane];
      s2b += f2[(size_t)ci[e+1]*16 + lane];
    }
    if (e < end) s2 += f2[(size_t)ci[e]*16 + lane];
    int d = end - beg;
    s2 = (s2 + s2b) / (float)(d > 0 ? d : 1);
  }
  O[(size_t)row*16 + lane] = s1 + s2 + ob[lane];
}

extern "C" void kernel_launch(void* const* d_in, const int* in_sizes, int n_in,
                              void* d_out, int out_size, void* d_ws, size_t ws_size,
                              hipStream_t stream)
{
  const float* x_p = (const float*)d_in[0];
  const int* pa_src=(const int*)d_in[3]; const int* pa_dst=(const int*)d_in[4];
  const int* ap_src=(const int*)d_in[5]; const int* ap_dst=(const int*)d_in[6];
  const int* ps_src=(const int*)d_in[7]; const int* ps_dst=(const int*)d_in[8];
  const int* sp_src=(const int*)d_in[9]; const int* sp_dst=(const int*)d_in[10];
  const float* ewp=(const float*)d_in[11]; const float* ebp=(const float*)d_in[12];
  const float* w0_pa=(const float*)d_in[17];
  const float* w0_ps=(const float*)d_in[19];
  const float* w1_ap=(const float*)d_in[22];
  const float* w1_sp=(const float*)d_in[24];
  const float* out_w=(const float*)d_in[25]; const float* out_b=(const float*)d_in[26];
  float* out = (float*)d_out;

  // ---- workspace layout (~44 MB; R1 proved ws_size >= ~94 MB) ----
  char* wp = (char*)d_ws;
  auto alloc = [&](size_t bytes) { char* p = wp; wp += (bytes + 255) & ~(size_t)255; return p; };
  float* yz     = (float*)alloc((size_t)NP*32*4);         // 12.8 MB
  int*   ci     = (int*)alloc((size_t)ETOT*4);            // 6.4 MB
  float* m16    = (float*)alloc((size_t)(NA+NS)*16*4);    // 3.52 MB
  u16*   wpk    = (u16*)alloc((size_t)256*128*2);
  float* WFi    = (float*)alloc((size_t)128*32*4);
  int*   h      = (int*)alloc((size_t)8*NT*4);            // 8.16 MB (memset)
  int*   rpo    = (int*)alloc((size_t)8*NT*4);            // 8.16 MB
  u16*   rank16 = (u16*)alloc((size_t)ETOT*2);            // 3.2 MB
  int*   rpG    = (int*)alloc((size_t)(NT+1)*4);
  int*   part   = (int*)alloc((size_t)64*4);

  // ---- K0: fold + pack + rank-recording histogram ----
  hipMemsetAsync(h, 0, (size_t)8*NT*4, stream);
  prep<<<HIST_BASE+NB_HIST,256,0,stream>>>(
      w0_pa, w1_ap, w0_ps, w1_sp, out_w, WFi, ewp, wpk,
      pa_dst, ps_dst, ap_dst, sp_dst, h, rank16);

  // ---- K1/K2: scans -> rp + per-bin rpo ----
  int nch = (NT + 4095)/4096;   // 63
  scan_partial<<<nch,256,0,stream>>>(h, NT, part);
  scan_chunk  <<<nch,256,0,stream>>>(h, NT, part, rpG, rpo);

  // ---- K3: encoder || atomic-free CSR fill (co-grid) ----
  enc_fill<<<NB_ENC + NB_FILL,256,0,stream>>>(
      x_p, wpk, ebp, WFi, yz,
      pa_src, pa_dst, ps_src, ps_dst, ap_src, ap_dst, sp_src, sp_dst,
      rpo, rank16, ci);

  // ---- K4: author+subject 16-wide aggregation ----
  gather16<<<(((size_t)(NA+NS)*16)+255)/256,256,0,stream>>>(yz, rpG, ci, m16, NA+NS);

  // ---- K5: final paper aggregation + bias -> d_out ----
  gather2_16<<<(((size_t)NP*16)+255)/256,256,0,stream>>>(
      m16, rpG + ROW_AP,
      m16 + (size_t)NA*16, rpG + ROW_SP,
      ci, out_b, out, NP);
}

// Round 9
// 313.923 us; speedup vs baseline: 1.1525x; 1.1525x over previous
//
#include <hip/hip_runtime.h>
#include <math.h>

constexpr int NP = 100000, NA = 50000, NS = 5000;
constexpr int EPA = 600000, EAP = 600000, EPS = 200000, ESP = 200000;
// concatenated relation order: pa | ps | ap | sp   (dst spaces: A | S | P | P)
constexpr int ETOT = EPA + EPS + EAP + ESP;            // 1.6M
constexpr int NT   = NA + NS + NP + NP;                // 255000 global dst rows
constexpr int OFF_PS = EPA, OFF_AP = EPA + EPS, OFF_SP = EPA + EPS + EAP;
constexpr int ROW_PS = NA, ROW_AP = NA + NS, ROW_SP = NA + NS + NP;

constexpr int NB_FOLD = 2;
constexpr int NB_PACK = (256*128)/256;          // 128
constexpr int NB_HIST = (ETOT + 1023)/1024;     // 1563 (4 edges/thread)
constexpr int HIST_BASE = NB_FOLD + NB_PACK;    // 130
constexpr int NB_ENC  = (NP + 63)/64;           // 1563
constexpr int NB_FILL = (ETOT + 1023)/1024;     // 1563

typedef short s16x8 __attribute__((ext_vector_type(8)));
typedef float f32x4 __attribute__((ext_vector_type(4)));
typedef unsigned short u16;

__device__ __forceinline__ float gelu_f(float x) {
  float x3 = x*x*x;
  return 0.5f*x*(1.0f + tanhf(0.7978845608028654f*(x + 0.044715f*x3)));
}
__device__ __forceinline__ u16 f2bf(float f) {
  unsigned u = __float_as_uint(f);
  u += 0x7fffu + ((u >> 16) & 1u);     // RNE
  return (u16)(u >> 16);
}
__device__ __forceinline__ float bf2f(u16 s) {
  return __uint_as_float((unsigned)s << 16);
}

// ================= K0: fold | pack | rank-recording histogram (single bin) =================
// b<2: fold (WFi = w0 @ (w1 @ out_w), interleaved [128][32])
// b<130: pack encoder W into MFMA fragment order
// else: h[row]++ (1 MB L2-hot) and record each edge's arrival rank (u16, coalesced)
__global__ __launch_bounds__(256) void prep(
    const float* __restrict__ w0_pa, const float* __restrict__ w1_ap,
    const float* __restrict__ w0_ps, const float* __restrict__ w1_sp,
    const float* __restrict__ out_w, float* __restrict__ WFi,
    const float* __restrict__ ewp, u16* __restrict__ wpk,
    const int* __restrict__ pa_d, const int* __restrict__ ps_d,
    const int* __restrict__ ap_d, const int* __restrict__ sp_d,
    int* __restrict__ h, u16* __restrict__ rank16)
{
  __shared__ float Wst[64*132];
  __shared__ float OW[128*16];
  __shared__ float U[128*16];
  const int b = blockIdx.x, tid = threadIdx.x;

  if (b >= HIST_BASE) {
    const int hblk = b - HIST_BASE;
    const int e = hblk*1024 + tid*4;
    if (e >= ETOT) return;
    const int* dsts; int off;
    if (e < OFF_PS)      { dsts = pa_d;          off = 0; }
    else if (e < OFF_AP) { dsts = ps_d - OFF_PS; off = ROW_PS; }
    else if (e < OFF_SP) { dsts = ap_d - OFF_AP; off = ROW_AP; }
    else                 { dsts = sp_d - OFF_SP; off = ROW_SP; }
    int4 d4 = *(const int4*)(dsts + e);
    unsigned p0 = (unsigned)atomicAdd(&h[off + d4.x], 1);
    unsigned p1 = (unsigned)atomicAdd(&h[off + d4.y], 1);
    unsigned p2 = (unsigned)atomicAdd(&h[off + d4.z], 1);
    unsigned p3 = (unsigned)atomicAdd(&h[off + d4.w], 1);
    uint2 rr;
    rr.x = (p0 & 0xffffu) | (p1 << 16);
    rr.y = (p2 & 0xffffu) | (p3 << 16);
    *(uint2*)(rank16 + e) = rr;
    return;
  }
  if (b >= NB_FOLD) {
    int o = (b - NB_FOLD)*256 + tid;
    int bb = o & 7;
    int l  = (o >> 3) & 63;
    int cf = (o >> 9) & 7;
    int ks = o >> 12;
    wpk[o] = f2bf(ewp[(ks*32 + (l>>4)*8 + bb)*128 + cf*16 + (l & 15)]);
    return;
  }

  // ---- fold role ----
  const float* w0 = (b == 0) ? w0_pa : w0_ps;
  const float* w1 = (b == 0) ? w1_ap : w1_sp;
  for (int i = tid; i < 512; i += 256) ((float4*)OW)[i] = ((const float4*)out_w)[i];
  for (int half = 0; half < 2; ++half) {
    __syncthreads();
    for (int i = tid; i < 64*32; i += 256) {
      int row = i >> 5, q = i & 31;
      float4 v = ((const float4*)(w1 + (size_t)(half*64 + row)*128))[q];
      *(float4*)&Wst[row*132 + q*4] = v;
    }
    __syncthreads();
    #pragma unroll
    for (int i = 0; i < 4; ++i) {
      int idx = tid + 256*i;
      int r = idx >> 4, c = idx & 15;
      float acc = 0.f;
      #pragma unroll 8
      for (int k = 0; k < 128; ++k) acc = fmaf(Wst[r*132+k], OW[k*16+c], acc);
      U[(half*64 + r)*16 + c] = acc;
    }
  }
  for (int half = 0; half < 2; ++half) {
    __syncthreads();
    for (int i = tid; i < 64*32; i += 256) {
      int row = i >> 5, q = i & 31;
      float4 v = ((const float4*)(w0 + (size_t)(half*64 + row)*128))[q];
      *(float4*)&Wst[row*132 + q*4] = v;
    }
    __syncthreads();
    #pragma unroll
    for (int i = 0; i < 4; ++i) {
      int idx = tid + 256*i;
      int r = idx >> 4, c = idx & 15;
      float acc = 0.f;
      #pragma unroll 8
      for (int k = 0; k < 128; ++k) acc = fmaf(Wst[r*132+k], U[k*16+c], acc);
      WFi[(half*64 + r)*32 + b*16 + c] = acc;
    }
  }
}

// ================= scans =================
__global__ __launch_bounds__(256) void scan_partial(const int* __restrict__ in, int n,
                                                    int* __restrict__ part) {
  __shared__ int red[4];
  int base = blockIdx.x*4096;
  int sum = 0;
  for (int i = threadIdx.x; i < 4096; i += 256) {
    int idx = base + i;
    sum += (idx < n) ? in[idx] : 0;
  }
  #pragma unroll
  for (int off = 32; off; off >>= 1) sum += __shfl_down(sum, off, 64);
  if ((threadIdx.x & 63) == 0) red[threadIdx.x >> 6] = sum;
  __syncthreads();
  if (threadIdx.x == 0) part[blockIdx.x] = red[0]+red[1]+red[2]+red[3];
}

__global__ __launch_bounds__(256) void scan_chunk(const int* __restrict__ in, int n,
    const int* __restrict__ part, int* __restrict__ out)
{
  int off0 = 0;
  for (int i = 0; i < (int)blockIdx.x; ++i) off0 += part[i];
  const int base = blockIdx.x*4096 + threadIdx.x*16;
  int loc[16]; int s = 0;
  #pragma unroll
  for (int j = 0; j < 16; ++j) {
    int idx = base + j;
    int v = (idx < n) ? in[idx] : 0;
    loc[j] = s; s += v;
  }
  __shared__ int ts[256];
  ts[threadIdx.x] = s; __syncthreads();
  for (int off = 1; off < 256; off <<= 1) {
    int t = (threadIdx.x >= off) ? ts[threadIdx.x - off] : 0;
    __syncthreads();
    ts[threadIdx.x] += t;
    __syncthreads();
  }
  int excl = off0 + ts[threadIdx.x] - s;
  #pragma unroll
  for (int j = 0; j < 16; ++j) {
    int idx = base + j;
    if (idx < n) out[idx] = excl + loc[j];
    if (idx == n-1) out[n] = excl + loc[j] + in[idx];
  }
}

// ================= K3: fused encoder || CSR fill (atomic-free, L2-hot tables) =================
// b odd: encoder block; b even: fill block.
__global__ __launch_bounds__(256) void enc_fill(
    const float* __restrict__ A, const u16* __restrict__ Wp,
    const float* __restrict__ bias, const float* __restrict__ WFi,
    float* __restrict__ YZ,
    const int* __restrict__ pa_s, const int* __restrict__ pa_d,
    const int* __restrict__ ps_s, const int* __restrict__ ps_d,
    const int* __restrict__ ap_s, const int* __restrict__ ap_d,
    const int* __restrict__ sp_s, const int* __restrict__ sp_d,
    const int* __restrict__ rp, const u16* __restrict__ rank16,
    int* __restrict__ ci)
{
  __shared__ u16 hl[64][132];
  const int b = blockIdx.x;
  const int tid = threadIdx.x;

  if (!(b & 1)) {
    // ---- fill role: slot = rp[row] + rank (no atomics; rp is 1MB L2-hot) ----
    const int fb = b >> 1;
    const int e = fb*1024 + tid*4;
    if (e >= ETOT) return;
    const int *srcs, *dsts; int off;
    if (e < OFF_PS)      { srcs = pa_s;          dsts = pa_d;          off = 0; }
    else if (e < OFF_AP) { srcs = ps_s - OFF_PS; dsts = ps_d - OFF_PS; off = ROW_PS; }
    else if (e < OFF_SP) { srcs = ap_s - OFF_AP; dsts = ap_d - OFF_AP; off = ROW_AP; }
    else                 { srcs = sp_s - OFF_SP; dsts = sp_d - OFF_SP; off = ROW_SP; }
    int4 s4 = *(const int4*)(srcs + e);
    int4 d4 = *(const int4*)(dsts + e);
    uint2 rr = *(const uint2*)(rank16 + e);
    ci[rp[off + d4.x] + (int)(rr.x & 0xffffu)] = s4.x;
    ci[rp[off + d4.y] + (int)(rr.x >> 16)]     = s4.y;
    ci[rp[off + d4.z] + (int)(rr.y & 0xffffu)] = s4.z;
    ci[rp[off + d4.w] + (int)(rr.y >> 16)]     = s4.w;
    return;
  }

  // ---- encoder role: yz = gelu(x_p @ Wenc + b) @ [Wao|Wso] ----
  const int eb = b >> 1;
  const int lane = tid & 63, wv = tid >> 6;
  const int rowbase = eb*64 + wv*16;
  const int m  = lane & 15;
  const int kq = lane >> 4;

  f32x4 acc[8];
  #pragma unroll
  for (int j = 0; j < 8; ++j) acc[j] = (f32x4){0.f,0.f,0.f,0.f};

  const int r0 = rowbase + m;
  const bool v0 = r0 < NP;
  const float* Arow = A + (size_t)r0*256 + kq*8;

  #pragma unroll
  for (int ks = 0; ks < 8; ++ks) {
    s16x8 a0 = {0,0,0,0,0,0,0,0};
    if (v0) {
      float4 f = *(const float4*)(Arow + ks*32);
      float4 g = *(const float4*)(Arow + ks*32 + 4);
      a0[0]=(short)f2bf(f.x); a0[1]=(short)f2bf(f.y); a0[2]=(short)f2bf(f.z); a0[3]=(short)f2bf(f.w);
      a0[4]=(short)f2bf(g.x); a0[5]=(short)f2bf(g.y); a0[6]=(short)f2bf(g.z); a0[7]=(short)f2bf(g.w);
    }
    const s16x8* Wf = (const s16x8*)Wp + (size_t)ks*512 + lane;
    #pragma unroll
    for (int cf = 0; cf < 8; ++cf)
      acc[cf] = __builtin_amdgcn_mfma_f32_16x16x32_bf16(a0, Wf[cf*64], acc[cf], 0, 0, 0);
  }

  // h -> LDS (bf16); D layout: col = lane&15, row-in-tile = kq*4 + r
  const int rlb = wv*16 + kq*4;
  #pragma unroll
  for (int cf = 0; cf < 8; ++cf) {
    const int col = cf*16 + m;
    const float bcol = bias[col];
    #pragma unroll
    for (int r = 0; r < 4; ++r)
      hl[rlb + r][col] = f2bf(gelu_f(acc[cf][r] + bcol));
  }
  __syncthreads();

  // yz[row][0..31] = h[row] @ WFi ; WFi read from global (16KB, L1-hot)
  const int r = tid >> 2;
  const int cg = (tid & 3) * 8;
  const int grow = eb*64 + r;
  if (grow >= NP) return;
  float s[8];
  #pragma unroll
  for (int j = 0; j < 8; ++j) s[j] = 0.f;
  #pragma unroll 4
  for (int k = 0; k < 128; ++k) {
    const float hv = bf2f(hl[r][k]);
    const float* wk = WFi + k*32 + cg;
    #pragma unroll
    for (int j = 0; j < 8; ++j) s[j] = fmaf(hv, wk[j], s[j]);
  }
  float* O = YZ + (size_t)grow*32 + cg;
  *(float4*)(O)   = make_float4(s[0], s[1], s[2], s[3]);
  *(float4*)(O+4) = make_float4(s[4], s[5], s[6], s[7]);
}

// ================= 16-wide gathers =================
__global__ __launch_bounds__(256) void gather16(const float* __restrict__ yz,
    const int* __restrict__ rp, const int* __restrict__ ci,
    float* __restrict__ m16, int n)
{
  int t = blockIdx.x*256 + threadIdx.x;
  int row = t >> 4, lane = t & 15;
  if (row >= n) return;
  int beg = rp[row], end = rp[row+1];
  int off = (row < NA ? 0 : 16) + lane;
  float a = 0.f, b = 0.f;
  int e = beg;
  for (; e + 1 < end; e += 2) {
    a += yz[(size_t)ci[e]  *32 + off];
    b += yz[(size_t)ci[e+1]*32 + off];
  }
  if (e < end) a += yz[(size_t)ci[e]*32 + off];
  int d = end - beg;
  m16[(size_t)row*16 + lane] = (a + b) / (float)(d > 0 ? d : 1);
}

__global__ __launch_bounds__(256) void gather2_16(
    const float* __restrict__ f1, const int* __restrict__ rp1,
    const float* __restrict__ f2, const int* __restrict__ rp2,
    const int* __restrict__ ci, const float* __restrict__ ob,
    float* __restrict__ O, int n)
{
  int t = blockIdx.x*256 + threadIdx.x;
  int row = t >> 4, lane = t & 15;
  if (row >= n) return;

  float s1 = 0.f, s1b = 0.f;
  {
    int beg = rp1[row], end = rp1[row+1];
    int e = beg;
    for (; e + 1 < end; e += 2) {
      s1  += f1[(size_t)ci[e]  *16 + lane];
      s1b += f1[(size_t)ci[e+1]*16 + lane];
    }
    if (e < end) s1 += f1[(size_t)ci[e]*16 + lane];
    int d = end - beg;
    s1 = (s1 + s1b) / (float)(d > 0 ? d : 1);
  }
  float s2 = 0.f, s2b = 0.f;
  {
    int beg = rp2[row], end = rp2[row+1];
    int e = beg;
    for (; e + 1 < end; e += 2) {
      s2  += f2[(size_t)ci[e]  *16 + lane];
      s2b += f2[(size_t)ci[e+1]*16 + lane];
    }
    if (e < end) s2 += f2[(size_t)ci[e]*16 + lane];
    int d = end - beg;
    s2 = (s2 + s2b) / (float)(d > 0 ? d : 1);
  }
  O[(size_t)row*16 + lane] = s1 + s2 + ob[lane];
}

extern "C" void kernel_launch(void* const* d_in, const int* in_sizes, int n_in,
                              void* d_out, int out_size, void* d_ws, size_t ws_size,
                              hipStream_t stream)
{
  const float* x_p = (const float*)d_in[0];
  const int* pa_src=(const int*)d_in[3]; const int* pa_dst=(const int*)d_in[4];
  const int* ap_src=(const int*)d_in[5]; const int* ap_dst=(const int*)d_in[6];
  const int* ps_src=(const int*)d_in[7]; const int* ps_dst=(const int*)d_in[8];
  const int* sp_src=(const int*)d_in[9]; const int* sp_dst=(const int*)d_in[10];
  const float* ewp=(const float*)d_in[11]; const float* ebp=(const float*)d_in[12];
  const float* w0_pa=(const float*)d_in[17];
  const float* w0_ps=(const float*)d_in[19];
  const float* w1_ap=(const float*)d_in[22];
  const float* w1_sp=(const float*)d_in[24];
  const float* out_w=(const float*)d_in[25]; const float* out_b=(const float*)d_in[26];
  float* out = (float*)d_out;

  // ---- workspace layout (~28 MB) ----
  char* wp = (char*)d_ws;
  auto alloc = [&](size_t bytes) { char* p = wp; wp += (bytes + 255) & ~(size_t)255; return p; };
  float* yz     = (float*)alloc((size_t)NP*32*4);         // 12.8 MB
  int*   ci     = (int*)alloc((size_t)ETOT*4);            // 6.4 MB
  float* m16    = (float*)alloc((size_t)(NA+NS)*16*4);    // 3.52 MB
  u16*   wpk    = (u16*)alloc((size_t)256*128*2);
  float* WFi    = (float*)alloc((size_t)128*32*4);
  int*   h      = (int*)alloc((size_t)NT*4);              // 1.02 MB (memset)
  u16*   rank16 = (u16*)alloc((size_t)ETOT*2);            // 3.2 MB
  int*   rpG    = (int*)alloc((size_t)(NT+1)*4);
  int*   part   = (int*)alloc((size_t)64*4);

  // ---- K0: fold + pack + rank-recording histogram (single 1MB table) ----
  hipMemsetAsync(h, 0, (size_t)NT*4, stream);
  prep<<<HIST_BASE+NB_HIST,256,0,stream>>>(
      w0_pa, w1_ap, w0_ps, w1_sp, out_w, WFi, ewp, wpk,
      pa_dst, ps_dst, ap_dst, sp_dst, h, rank16);

  // ---- K1/K2: scans -> rowptr ----
  int nch = (NT + 4095)/4096;   // 63
  scan_partial<<<nch,256,0,stream>>>(h, NT, part);
  scan_chunk  <<<nch,256,0,stream>>>(h, NT, part, rpG);

  // ---- K3: encoder || atomic-free CSR fill (co-grid) ----
  enc_fill<<<NB_ENC + NB_FILL,256,0,stream>>>(
      x_p, wpk, ebp, WFi, yz,
      pa_src, pa_dst, ps_src, ps_dst, ap_src, ap_dst, sp_src, sp_dst,
      rpG, rank16, ci);

  // ---- K4: author+subject 16-wide aggregation ----
  gather16<<<(((size_t)(NA+NS)*16)+255)/256,256,0,stream>>>(yz, rpG, ci, m16, NA+NS);

  // ---- K5: final paper aggregation + bias -> d_out ----
  gather2_16<<<(((size_t)NP*16)+255)/256,256,0,stream>>>(
      m16, rpG + ROW_AP,
      m16 + (size_t)NA*16, rpG + ROW_SP,
      ci, out_b, out, NP);
}

// Round 10
// 219.469 us; speedup vs baseline: 1.6485x; 1.4304x over previous
//
#include <hip/hip_runtime.h>
#include <math.h>

constexpr int NP = 100000, NA = 50000, NS = 5000;
constexpr int EPA = 600000, EAP = 600000, EPS = 200000, ESP = 200000;
// concatenated relation order: pa | ps | ap | sp   (dst spaces: A | S | P | P)
constexpr int ETOT = EPA + EPS + EAP + ESP;            // 1.6M
constexpr int NT   = NA + NS + NP + NP;                // 255000 global dst rows
constexpr int OFF_PS = EPA, OFF_AP = EPA + EPS, OFF_SP = EPA + EPS + EAP;
constexpr int ROW_PS = NA, ROW_AP = NA + NS, ROW_SP = NA + NS + NP;

constexpr int NB_FOLD = 2;
constexpr int NB_PACK = (256*128)/256;          // 128
constexpr int NB_HIST = (ETOT + 1023)/1024;     // 1563 (4 edges/thread)
constexpr int HIST_BASE = NB_FOLD + NB_PACK;    // 130
constexpr int NB_ENC  = (NP + 63)/64;           // 1563
constexpr int NB_FILL = (ETOT + 1023)/1024;     // 1563

typedef short s16x8 __attribute__((ext_vector_type(8)));
typedef float f32x4 __attribute__((ext_vector_type(4)));
typedef unsigned short u16;

__device__ __forceinline__ float gelu_f(float x) {
  float x3 = x*x*x;
  return 0.5f*x*(1.0f + tanhf(0.7978845608028654f*(x + 0.044715f*x3)));
}
__device__ __forceinline__ u16 f2bf(float f) {
  unsigned u = __float_as_uint(f);
  u += 0x7fffu + ((u >> 16) & 1u);     // RNE
  return (u16)(u >> 16);
}
__device__ __forceinline__ float bf2f(u16 s) {
  return __uint_as_float((unsigned)s << 16);
}

// ================= K0: fold | pack | rank-recording histogram =================
// b<2: fold -> WFb bf16 B-fragments of WF = w0 @ (w1 @ out_w)
//   WFb[((ks*2+cf)*64 + l)*8 + bb] = bf16(WF[ks*32 + (l>>4)*8 + bb][cf*16 + (l&15)]), cf = b
// b<130: pack encoder W into MFMA A/B fragment order
// else: h[row]++ (1 MB L2-hot) and record each edge's arrival rank (u16, coalesced)
__global__ __launch_bounds__(256) void prep(
    const float* __restrict__ w0_pa, const float* __restrict__ w1_ap,
    const float* __restrict__ w0_ps, const float* __restrict__ w1_sp,
    const float* __restrict__ out_w, u16* __restrict__ WFb,
    const float* __restrict__ ewp, u16* __restrict__ wpk,
    const int* __restrict__ pa_d, const int* __restrict__ ps_d,
    const int* __restrict__ ap_d, const int* __restrict__ sp_d,
    int* __restrict__ h, u16* __restrict__ rank16)
{
  __shared__ float Wst[64*132];
  __shared__ float OW[128*16];
  __shared__ float U[128*16];
  const int b = blockIdx.x, tid = threadIdx.x;

  if (b >= HIST_BASE) {
    const int hblk = b - HIST_BASE;
    const int e = hblk*1024 + tid*4;
    if (e >= ETOT) return;
    const int* dsts; int off;
    if (e < OFF_PS)      { dsts = pa_d;          off = 0; }
    else if (e < OFF_AP) { dsts = ps_d - OFF_PS; off = ROW_PS; }
    else if (e < OFF_SP) { dsts = ap_d - OFF_AP; off = ROW_AP; }
    else                 { dsts = sp_d - OFF_SP; off = ROW_SP; }
    int4 d4 = *(const int4*)(dsts + e);
    unsigned p0 = (unsigned)atomicAdd(&h[off + d4.x], 1);
    unsigned p1 = (unsigned)atomicAdd(&h[off + d4.y], 1);
    unsigned p2 = (unsigned)atomicAdd(&h[off + d4.z], 1);
    unsigned p3 = (unsigned)atomicAdd(&h[off + d4.w], 1);
    uint2 rr;
    rr.x = (p0 & 0xffffu) | (p1 << 16);
    rr.y = (p2 & 0xffffu) | (p3 << 16);
    *(uint2*)(rank16 + e) = rr;
    return;
  }
  if (b >= NB_FOLD) {
    int o = (b - NB_FOLD)*256 + tid;
    int bb = o & 7;
    int l  = (o >> 3) & 63;
    int cf = (o >> 9) & 7;
    int ks = o >> 12;
    wpk[o] = f2bf(ewp[(ks*32 + (l>>4)*8 + bb)*128 + cf*16 + (l & 15)]);
    return;
  }

  // ---- fold role: WF = w0 @ (w1 @ out_w), emitted directly as bf16 B-fragments ----
  const float* w0 = (b == 0) ? w0_pa : w0_ps;
  const float* w1 = (b == 0) ? w1_ap : w1_sp;
  for (int i = tid; i < 512; i += 256) ((float4*)OW)[i] = ((const float4*)out_w)[i];
  for (int half = 0; half < 2; ++half) {
    __syncthreads();
    for (int i = tid; i < 64*32; i += 256) {
      int row = i >> 5, q = i & 31;
      float4 v = ((const float4*)(w1 + (size_t)(half*64 + row)*128))[q];
      *(float4*)&Wst[row*132 + q*4] = v;
    }
    __syncthreads();
    #pragma unroll
    for (int i = 0; i < 4; ++i) {
      int idx = tid + 256*i;
      int r = idx >> 4, c = idx & 15;
      float acc = 0.f;
      #pragma unroll 8
      for (int k = 0; k < 128; ++k) acc = fmaf(Wst[r*132+k], OW[k*16+c], acc);
      U[(half*64 + r)*16 + c] = acc;
    }
  }
  for (int half = 0; half < 2; ++half) {
    __syncthreads();
    for (int i = tid; i < 64*32; i += 256) {
      int row = i >> 5, q = i & 31;
      float4 v = ((const float4*)(w0 + (size_t)(half*64 + row)*128))[q];
      *(float4*)&Wst[row*132 + q*4] = v;
    }
    __syncthreads();
    #pragma unroll
    for (int i = 0; i < 4; ++i) {
      int idx = tid + 256*i;
      int r = idx >> 4, c = idx & 15;
      float acc = 0.f;
      #pragma unroll 8
      for (int k = 0; k < 128; ++k) acc = fmaf(Wst[r*132+k], U[k*16+c], acc);
      int k = half*64 + r;   // WF row index
      int ks = k >> 5;
      int lane = (((k >> 3) & 3) << 4) | c;
      WFb[(((size_t)ks*2 + b)*64 + lane)*8 + (k & 7)] = f2bf(acc);
    }
  }
}

// ================= scans =================
__global__ __launch_bounds__(256) void scan_partial(const int* __restrict__ in, int n,
                                                    int* __restrict__ part) {
  __shared__ int red[4];
  int base = blockIdx.x*4096;
  int sum = 0;
  for (int i = threadIdx.x; i < 4096; i += 256) {
    int idx = base + i;
    sum += (idx < n) ? in[idx] : 0;
  }
  #pragma unroll
  for (int off = 32; off; off >>= 1) sum += __shfl_down(sum, off, 64);
  if ((threadIdx.x & 63) == 0) red[threadIdx.x >> 6] = sum;
  __syncthreads();
  if (threadIdx.x == 0) part[blockIdx.x] = red[0]+red[1]+red[2]+red[3];
}

__global__ __launch_bounds__(256) void scan_chunk(const int* __restrict__ in, int n,
    const int* __restrict__ part, int* __restrict__ out)
{
  int off0 = 0;
  for (int i = 0; i < (int)blockIdx.x; ++i) off0 += part[i];
  const int base = blockIdx.x*4096 + threadIdx.x*16;
  int loc[16]; int s = 0;
  #pragma unroll
  for (int j = 0; j < 16; ++j) {
    int idx = base + j;
    int v = (idx < n) ? in[idx] : 0;
    loc[j] = s; s += v;
  }
  __shared__ int ts[256];
  ts[threadIdx.x] = s; __syncthreads();
  for (int off = 1; off < 256; off <<= 1) {
    int t = (threadIdx.x >= off) ? ts[threadIdx.x - off] : 0;
    __syncthreads();
    ts[threadIdx.x] += t;
    __syncthreads();
  }
  int excl = off0 + ts[threadIdx.x] - s;
  #pragma unroll
  for (int j = 0; j < 16; ++j) {
    int idx = base + j;
    if (idx < n) out[idx] = excl + loc[j];
    if (idx == n-1) out[n] = excl + loc[j] + in[idx];
  }
}

// ================= K3: fused encoder || CSR fill =================
// b odd: encoder block (yz via MFMA end-to-end); b even: atomic-free fill block.
__global__ __launch_bounds__(256) void enc_fill(
    const float* __restrict__ A, const u16* __restrict__ Wp,
    const float* __restrict__ bias, const u16* __restrict__ WFb,
    float* __restrict__ YZ,
    const int* __restrict__ pa_s, const int* __restrict__ pa_d,
    const int* __restrict__ ps_s, const int* __restrict__ ps_d,
    const int* __restrict__ ap_s, const int* __restrict__ ap_d,
    const int* __restrict__ sp_s, const int* __restrict__ sp_d,
    const int* __restrict__ rp, const u16* __restrict__ rank16,
    int* __restrict__ ci)
{
  __shared__ u16 hl[64][136];   // stride 136 u16 = 272 B (16B-aligned rows for b128 reads)
  const int b = blockIdx.x;
  const int tid = threadIdx.x;

  if (!(b & 1)) {
    // ---- fill role: slot = rp[row] + rank (no atomics; rp/rank L2-hot) ----
    const int fb = b >> 1;
    const int e = fb*1024 + tid*4;
    if (e >= ETOT) return;
    const int *srcs, *dsts; int off;
    if (e < OFF_PS)      { srcs = pa_s;          dsts = pa_d;          off = 0; }
    else if (e < OFF_AP) { srcs = ps_s - OFF_PS; dsts = ps_d - OFF_PS; off = ROW_PS; }
    else if (e < OFF_SP) { srcs = ap_s - OFF_AP; dsts = ap_d - OFF_AP; off = ROW_AP; }
    else                 { srcs = sp_s - OFF_SP; dsts = sp_d - OFF_SP; off = ROW_SP; }
    int4 s4 = *(const int4*)(srcs + e);
    int4 d4 = *(const int4*)(dsts + e);
    uint2 rr = *(const uint2*)(rank16 + e);
    ci[rp[off + d4.x] + (int)(rr.x & 0xffffu)] = s4.x;
    ci[rp[off + d4.y] + (int)(rr.x >> 16)]     = s4.y;
    ci[rp[off + d4.z] + (int)(rr.y & 0xffffu)] = s4.z;
    ci[rp[off + d4.w] + (int)(rr.y >> 16)]     = s4.w;
    return;
  }

  // ---- encoder role: yz = gelu(x_p @ Wenc + b) @ WF, all MFMA ----
  const int eb = b >> 1;
  const int lane = tid & 63, wv = tid >> 6;
  const int rowbase = eb*64 + wv*16;
  const int m  = lane & 15;
  const int kq = lane >> 4;

  f32x4 acc[8];
  #pragma unroll
  for (int j = 0; j < 8; ++j) acc[j] = (f32x4){0.f,0.f,0.f,0.f};

  const int r0 = rowbase + m;
  const bool v0 = r0 < NP;
  const float* Arow = A + (size_t)r0*256 + kq*8;

  #pragma unroll
  for (int ks = 0; ks < 8; ++ks) {
    s16x8 a0 = {0,0,0,0,0,0,0,0};
    if (v0) {
      float4 f = *(const float4*)(Arow + ks*32);
      float4 g = *(const float4*)(Arow + ks*32 + 4);
      a0[0]=(short)f2bf(f.x); a0[1]=(short)f2bf(f.y); a0[2]=(short)f2bf(f.z); a0[3]=(short)f2bf(f.w);
      a0[4]=(short)f2bf(g.x); a0[5]=(short)f2bf(g.y); a0[6]=(short)f2bf(g.z); a0[7]=(short)f2bf(g.w);
    }
    const s16x8* Wf = (const s16x8*)Wp + (size_t)ks*512 + lane;
    #pragma unroll
    for (int cf = 0; cf < 8; ++cf)
      acc[cf] = __builtin_amdgcn_mfma_f32_16x16x32_bf16(a0, Wf[cf*64], acc[cf], 0, 0, 0);
  }

  // h -> LDS (bf16); D layout: col = lane&15, row-in-tile = kq*4 + r
  const int rlb = wv*16 + kq*4;
  #pragma unroll
  for (int cf = 0; cf < 8; ++cf) {
    const int col = cf*16 + m;
    const float bcol = bias[col];
    #pragma unroll
    for (int r = 0; r < 4; ++r)
      hl[rlb + r][col] = f2bf(gelu_f(acc[cf][r] + bcol));
  }
  __syncthreads();

  // yz tile = h_tile(16x128) @ WF(128x32) via 8 MFMAs.
  // A-frag: lane holds h[row = m][k = ks*32 + kq*8 + bb]  -> one b128 LDS read per ks.
  const s16x8* WFv = (const s16x8*)WFb;
  f32x4 yacc[2];
  yacc[0] = (f32x4){0.f,0.f,0.f,0.f};
  yacc[1] = (f32x4){0.f,0.f,0.f,0.f};
  #pragma unroll
  for (int ks = 0; ks < 4; ++ks) {
    s16x8 af = *(const s16x8*)&hl[wv*16 + m][ks*32 + kq*8];
    yacc[0] = __builtin_amdgcn_mfma_f32_16x16x32_bf16(af, WFv[(ks*2+0)*64 + lane], yacc[0], 0, 0, 0);
    yacc[1] = __builtin_amdgcn_mfma_f32_16x16x32_bf16(af, WFv[(ks*2+1)*64 + lane], yacc[1], 0, 0, 0);
  }

  // D layout: col = cf*16 + m, row = rowbase + kq*4 + r
  #pragma unroll
  for (int r = 0; r < 4; ++r) {
    const int row = rowbase + kq*4 + r;
    if (row < NP) {
      YZ[(size_t)row*32 + m]      = yacc[0][r];
      YZ[(size_t)row*32 + 16 + m] = yacc[1][r];
    }
  }
}

// ================= 16-wide gathers =================
__global__ __launch_bounds__(256) void gather16(const float* __restrict__ yz,
    const int* __restrict__ rp, const int* __restrict__ ci,
    float* __restrict__ m16, int n)
{
  int t = blockIdx.x*256 + threadIdx.x;
  int row = t >> 4, lane = t & 15;
  if (row >= n) return;
  int beg = rp[row], end = rp[row+1];
  int off = (row < NA ? 0 : 16) + lane;
  float a = 0.f, b = 0.f;
  int e = beg;
  for (; e + 1 < end; e += 2) {
    a += yz[(size_t)ci[e]  *32 + off];
    b += yz[(size_t)ci[e+1]*32 + off];
  }
  if (e < end) a += yz[(size_t)ci[e]*32 + off];
  int d = end - beg;
  m16[(size_t)row*16 + lane] = (a + b) / (float)(d > 0 ? d : 1);
}

__global__ __launch_bounds__(256) void gather2_16(
    const float* __restrict__ f1, const int* __restrict__ rp1,
    const float* __restrict__ f2, const int* __restrict__ rp2,
    const int* __restrict__ ci, const float* __restrict__ ob,
    float* __restrict__ O, int n)
{
  int t = blockIdx.x*256 + threadIdx.x;
  int row = t >> 4, lane = t & 15;
  if (row >= n) return;

  float s1 = 0.f, s1b = 0.f;
  {
    int beg = rp1[row], end = rp1[row+1];
    int e = beg;
    for (; e + 1 < end; e += 2) {
      s1  += f1[(size_t)ci[e]  *16 + lane];
      s1b += f1[(size_t)ci[e+1]*16 + lane];
    }
    if (e < end) s1 += f1[(size_t)ci[e]*16 + lane];
    int d = end - beg;
    s1 = (s1 + s1b) / (float)(d > 0 ? d : 1);
  }
  float s2 = 0.f, s2b = 0.f;
  {
    int beg = rp2[row], end = rp2[row+1];
    int e = beg;
    for (; e + 1 < end; e += 2) {
      s2  += f2[(size_t)ci[e]  *16 + lane];
      s2b += f2[(size_t)ci[e+1]*16 + lane];
    }
    if (e < end) s2 += f2[(size_t)ci[e]*16 + lane];
    int d = end - beg;
    s2 = (s2 + s2b) / (float)(d > 0 ? d : 1);
  }
  O[(size_t)row*16 + lane] = s1 + s2 + ob[lane];
}

extern "C" void kernel_launch(void* const* d_in, const int* in_sizes, int n_in,
                              void* d_out, int out_size, void* d_ws, size_t ws_size,
                              hipStream_t stream)
{
  const float* x_p = (const float*)d_in[0];
  const int* pa_src=(const int*)d_in[3]; const int* pa_dst=(const int*)d_in[4];
  const int* ap_src=(const int*)d_in[5]; const int* ap_dst=(const int*)d_in[6];
  const int* ps_src=(const int*)d_in[7]; const int* ps_dst=(const int*)d_in[8];
  const int* sp_src=(const int*)d_in[9]; const int* sp_dst=(const int*)d_in[10];
  const float* ewp=(const float*)d_in[11]; const float* ebp=(const float*)d_in[12];
  const float* w0_pa=(const float*)d_in[17];
  const float* w0_ps=(const float*)d_in[19];
  const float* w1_ap=(const float*)d_in[22];
  const float* w1_sp=(const float*)d_in[24];
  const float* out_w=(const float*)d_in[25]; const float* out_b=(const float*)d_in[26];
  float* out = (float*)d_out;

  // ---- workspace layout (~28 MB) ----
  char* wp = (char*)d_ws;
  auto alloc = [&](size_t bytes) { char* p = wp; wp += (bytes + 255) & ~(size_t)255; return p; };
  float* yz     = (float*)alloc((size_t)NP*32*4);         // 12.8 MB
  int*   ci     = (int*)alloc((size_t)ETOT*4);            // 6.4 MB
  float* m16    = (float*)alloc((size_t)(NA+NS)*16*4);    // 3.52 MB
  u16*   wpk    = (u16*)alloc((size_t)256*128*2);
  u16*   WFb    = (u16*)alloc((size_t)8*64*8*2);          // 8 KB bf16 B-frags
  int*   h      = (int*)alloc((size_t)NT*4);              // 1.02 MB (memset)
  u16*   rank16 = (u16*)alloc((size_t)ETOT*2);            // 3.2 MB
  int*   rpG    = (int*)alloc((size_t)(NT+1)*4);
  int*   part   = (int*)alloc((size_t)64*4);

  // ---- K0: fold + pack + rank-recording histogram ----
  hipMemsetAsync(h, 0, (size_t)NT*4, stream);
  prep<<<HIST_BASE+NB_HIST,256,0,stream>>>(
      w0_pa, w1_ap, w0_ps, w1_sp, out_w, WFb, ewp, wpk,
      pa_dst, ps_dst, ap_dst, sp_dst, h, rank16);

  // ---- K1/K2: scans -> rowptr ----
  int nch = (NT + 4095)/4096;   // 63
  scan_partial<<<nch,256,0,stream>>>(h, NT, part);
  scan_chunk  <<<nch,256,0,stream>>>(h, NT, part, rpG);

  // ---- K3: encoder || atomic-free CSR fill (co-grid) ----
  enc_fill<<<NB_ENC + NB_FILL,256,0,stream>>>(
      x_p, wpk, ebp, WFb, yz,
      pa_src, pa_dst, ps_src, ps_dst, ap_src, ap_dst, sp_src, sp_dst,
      rpG, rank16, ci);

  // ---- K4: author+subject 16-wide aggregation ----
  gather16<<<(((size_t)(NA+NS)*16)+255)/256,256,0,stream>>>(yz, rpG, ci, m16, NA+NS);

  // ---- K5: final paper aggregation + bias -> d_out ----
  gather2_16<<<(((size_t)NP*16)+255)/256,256,0,stream>>>(
      m16, rpG + ROW_AP,
      m16 + (size_t)NA*16, rpG + ROW_SP,
      ci, out_b, out, NP);
}

// Round 11
// 200.369 us; speedup vs baseline: 1.8057x; 1.0953x over previous
//
#include <hip/hip_runtime.h>
#include <math.h>

constexpr int NP = 100000, NA = 50000, NS = 5000;
constexpr int EPA = 600000, EAP = 600000, EPS = 200000, ESP = 200000;
// concatenated relation order: pa | ps | ap | sp   (dst spaces: A | S | P | P)
constexpr int ETOT = EPA + EPS + EAP + ESP;            // 1.6M
constexpr int NT   = NA + NS + NP + NP;                // 255000 global dst rows
constexpr int OFF_PS = EPA, OFF_AP = EPA + EPS, OFF_SP = EPA + EPS + EAP;
constexpr int ROW_PS = NA, ROW_AP = NA + NS, ROW_SP = NA + NS + NP;

constexpr int NB_FOLD  = 2;
constexpr int NB_PACK  = (256*128)/256;           // 128
constexpr int NB_HIST  = (ETOT + 1023)/1024;      // 1563 (4 edges/thread)
constexpr int NB_ENC   = (NP + 63)/64;            // 1563
constexpr int NB_FILLA = (OFF_AP + 1023)/1024;    // 782  (pa|ps half)
constexpr int NB_FILLB = ((ETOT-OFF_AP)+1023)/1024; // 782 (ap|sp half)
constexpr int NB_G16   = ((NA+NS)*16 + 255)/256;  // 3438

typedef short s16x8 __attribute__((ext_vector_type(8)));
typedef float f32x4 __attribute__((ext_vector_type(4)));
typedef unsigned short u16;

__device__ __forceinline__ float gelu_f(float x) {
  float x3 = x*x*x;
  return 0.5f*x*(1.0f + tanhf(0.7978845608028654f*(x + 0.044715f*x3)));
}
__device__ __forceinline__ u16 f2bf(float f) {
  unsigned u = __float_as_uint(f);
  u += 0x7fffu + ((u >> 16) & 1u);     // RNE
  return (u16)(u >> 16);
}
__device__ __forceinline__ float bf2f(u16 s) {
  return __uint_as_float((unsigned)s << 16);
}

// ================= K0: fold (WFb bf16 B-frags) + pack (wpk) =================
__global__ __launch_bounds__(256) void fold_pack(
    const float* __restrict__ w0_pa, const float* __restrict__ w1_ap,
    const float* __restrict__ w0_ps, const float* __restrict__ w1_sp,
    const float* __restrict__ out_w, u16* __restrict__ WFb,
    const float* __restrict__ ewp, u16* __restrict__ wpk)
{
  __shared__ float Wst[64*132];
  __shared__ float OW[128*16];
  __shared__ float U[128*16];
  const int b = blockIdx.x, tid = threadIdx.x;

  if (b >= NB_FOLD) {
    int o = (b - NB_FOLD)*256 + tid;
    int bb = o & 7;
    int l  = (o >> 3) & 63;
    int cf = (o >> 9) & 7;
    int ks = o >> 12;
    wpk[o] = f2bf(ewp[(ks*32 + (l>>4)*8 + bb)*128 + cf*16 + (l & 15)]);
    return;
  }

  // fold role: WF = w0 @ (w1 @ out_w), emitted as bf16 B-fragments (cf = b)
  const float* w0 = (b == 0) ? w0_pa : w0_ps;
  const float* w1 = (b == 0) ? w1_ap : w1_sp;
  for (int i = tid; i < 512; i += 256) ((float4*)OW)[i] = ((const float4*)out_w)[i];
  for (int half = 0; half < 2; ++half) {
    __syncthreads();
    for (int i = tid; i < 64*32; i += 256) {
      int row = i >> 5, q = i & 31;
      float4 v = ((const float4*)(w1 + (size_t)(half*64 + row)*128))[q];
      *(float4*)&Wst[row*132 + q*4] = v;
    }
    __syncthreads();
    #pragma unroll
    for (int i = 0; i < 4; ++i) {
      int idx = tid + 256*i;
      int r = idx >> 4, c = idx & 15;
      float acc = 0.f;
      #pragma unroll 8
      for (int k = 0; k < 128; ++k) acc = fmaf(Wst[r*132+k], OW[k*16+c], acc);
      U[(half*64 + r)*16 + c] = acc;
    }
  }
  for (int half = 0; half < 2; ++half) {
    __syncthreads();
    for (int i = tid; i < 64*32; i += 256) {
      int row = i >> 5, q = i & 31;
      float4 v = ((const float4*)(w0 + (size_t)(half*64 + row)*128))[q];
      *(float4*)&Wst[row*132 + q*4] = v;
    }
    __syncthreads();
    #pragma unroll
    for (int i = 0; i < 4; ++i) {
      int idx = tid + 256*i;
      int r = idx >> 4, c = idx & 15;
      float acc = 0.f;
      #pragma unroll 8
      for (int k = 0; k < 128; ++k) acc = fmaf(Wst[r*132+k], U[k*16+c], acc);
      int k = half*64 + r;   // WF row index
      int ks = k >> 5;
      int lane = (((k >> 3) & 3) << 4) | c;
      WFb[(((size_t)ks*2 + b)*64 + lane)*8 + (k & 7)] = f2bf(acc);
    }
  }
}

// ================= K1: rank-recording histogram || encoder =================
// b even: hist role; b odd: encoder role (yz = gelu(x_p@Wenc+b) @ WF, all MFMA)
__global__ __launch_bounds__(256) void hist_enc(
    const int* __restrict__ pa_d, const int* __restrict__ ps_d,
    const int* __restrict__ ap_d, const int* __restrict__ sp_d,
    int* __restrict__ h, u16* __restrict__ rank16,
    const float* __restrict__ A, const u16* __restrict__ Wp,
    const float* __restrict__ bias, const u16* __restrict__ WFb,
    float* __restrict__ YZ)
{
  __shared__ u16 hl[64][136];
  const int b = blockIdx.x;
  const int tid = threadIdx.x;

  if (!(b & 1)) {
    // ---- hist role: h[row]++ (1 MB L2-hot), record arrival rank (u16 coalesced) ----
    const int e = (b >> 1)*1024 + tid*4;
    if (e >= ETOT) return;
    const int* dsts; int off;
    if (e < OFF_PS)      { dsts = pa_d;          off = 0; }
    else if (e < OFF_AP) { dsts = ps_d - OFF_PS; off = ROW_PS; }
    else if (e < OFF_SP) { dsts = ap_d - OFF_AP; off = ROW_AP; }
    else                 { dsts = sp_d - OFF_SP; off = ROW_SP; }
    int4 d4 = *(const int4*)(dsts + e);
    unsigned p0 = (unsigned)atomicAdd(&h[off + d4.x], 1);
    unsigned p1 = (unsigned)atomicAdd(&h[off + d4.y], 1);
    unsigned p2 = (unsigned)atomicAdd(&h[off + d4.z], 1);
    unsigned p3 = (unsigned)atomicAdd(&h[off + d4.w], 1);
    uint2 rr;
    rr.x = (p0 & 0xffffu) | (p1 << 16);
    rr.y = (p2 & 0xffffu) | (p3 << 16);
    *(uint2*)(rank16 + e) = rr;
    return;
  }

  // ---- encoder role ----
  const int eb = b >> 1;
  const int lane = tid & 63, wv = tid >> 6;
  const int rowbase = eb*64 + wv*16;
  const int m  = lane & 15;
  const int kq = lane >> 4;

  f32x4 acc[8];
  #pragma unroll
  for (int j = 0; j < 8; ++j) acc[j] = (f32x4){0.f,0.f,0.f,0.f};

  const int r0 = rowbase + m;
  const bool v0 = r0 < NP;
  const float* Arow = A + (size_t)r0*256 + kq*8;

  #pragma unroll
  for (int ks = 0; ks < 8; ++ks) {
    s16x8 a0 = {0,0,0,0,0,0,0,0};
    if (v0) {
      float4 f = *(const float4*)(Arow + ks*32);
      float4 g = *(const float4*)(Arow + ks*32 + 4);
      a0[0]=(short)f2bf(f.x); a0[1]=(short)f2bf(f.y); a0[2]=(short)f2bf(f.z); a0[3]=(short)f2bf(f.w);
      a0[4]=(short)f2bf(g.x); a0[5]=(short)f2bf(g.y); a0[6]=(short)f2bf(g.z); a0[7]=(short)f2bf(g.w);
    }
    const s16x8* Wf = (const s16x8*)Wp + (size_t)ks*512 + lane;
    #pragma unroll
    for (int cf = 0; cf < 8; ++cf)
      acc[cf] = __builtin_amdgcn_mfma_f32_16x16x32_bf16(a0, Wf[cf*64], acc[cf], 0, 0, 0);
  }

  // h -> LDS (bf16); D layout: col = lane&15, row-in-tile = kq*4 + r
  const int rlb = wv*16 + kq*4;
  #pragma unroll
  for (int cf = 0; cf < 8; ++cf) {
    const int col = cf*16 + m;
    const float bcol = bias[col];
    #pragma unroll
    for (int r = 0; r < 4; ++r)
      hl[rlb + r][col] = f2bf(gelu_f(acc[cf][r] + bcol));
  }
  __syncthreads();

  // yz tile = h_tile(16x128) @ WF(128x32) via 8 MFMAs (A-frag straight from LDS)
  const s16x8* WFv = (const s16x8*)WFb;
  f32x4 yacc[2];
  yacc[0] = (f32x4){0.f,0.f,0.f,0.f};
  yacc[1] = (f32x4){0.f,0.f,0.f,0.f};
  #pragma unroll
  for (int ks = 0; ks < 4; ++ks) {
    s16x8 af = *(const s16x8*)&hl[wv*16 + m][ks*32 + kq*8];
    yacc[0] = __builtin_amdgcn_mfma_f32_16x16x32_bf16(af, WFv[(ks*2+0)*64 + lane], yacc[0], 0, 0, 0);
    yacc[1] = __builtin_amdgcn_mfma_f32_16x16x32_bf16(af, WFv[(ks*2+1)*64 + lane], yacc[1], 0, 0, 0);
  }
  #pragma unroll
  for (int r = 0; r < 4; ++r) {
    const int row = rowbase + kq*4 + r;
    if (row < NP) {
      YZ[(size_t)row*32 + m]      = yacc[0][r];
      YZ[(size_t)row*32 + 16 + m] = yacc[1][r];
    }
  }
}

// ================= scans =================
__global__ __launch_bounds__(256) void scan_partial(const int* __restrict__ in, int n,
                                                    int* __restrict__ part) {
  __shared__ int red[4];
  int base = blockIdx.x*4096;
  int sum = 0;
  for (int i = threadIdx.x; i < 4096; i += 256) {
    int idx = base + i;
    sum += (idx < n) ? in[idx] : 0;
  }
  #pragma unroll
  for (int off = 32; off; off >>= 1) sum += __shfl_down(sum, off, 64);
  if ((threadIdx.x & 63) == 0) red[threadIdx.x >> 6] = sum;
  __syncthreads();
  if (threadIdx.x == 0) part[blockIdx.x] = red[0]+red[1]+red[2]+red[3];
}

__global__ __launch_bounds__(256) void scan_chunk(const int* __restrict__ in, int n,
    const int* __restrict__ part, int* __restrict__ out)
{
  int off0 = 0;
  for (int i = 0; i < (int)blockIdx.x; ++i) off0 += part[i];
  const int base = blockIdx.x*4096 + threadIdx.x*16;
  int loc[16]; int s = 0;
  #pragma unroll
  for (int j = 0; j < 16; ++j) {
    int idx = base + j;
    int v = (idx < n) ? in[idx] : 0;
    loc[j] = s; s += v;
  }
  __shared__ int ts[256];
  ts[threadIdx.x] = s; __syncthreads();
  for (int off = 1; off < 256; off <<= 1) {
    int t = (threadIdx.x >= off) ? ts[threadIdx.x - off] : 0;
    __syncthreads();
    ts[threadIdx.x] += t;
    __syncthreads();
  }
  int excl = off0 + ts[threadIdx.x] - s;
  #pragma unroll
  for (int j = 0; j < 16; ++j) {
    int idx = base + j;
    if (idx < n) out[idx] = excl + loc[j];
    if (idx == n-1) out[n] = excl + loc[j] + in[idx];
  }
}

// ================= atomic-free CSR fill over edge range [e0, e1) =================
__device__ __forceinline__ void fill4(int e,
    const int* __restrict__ pa_s, const int* __restrict__ pa_d,
    const int* __restrict__ ps_s, const int* __restrict__ ps_d,
    const int* __restrict__ ap_s, const int* __restrict__ ap_d,
    const int* __restrict__ sp_s, const int* __restrict__ sp_d,
    const int* __restrict__ rp, const u16* __restrict__ rank16,
    int* __restrict__ ci)
{
  const int *srcs, *dsts; int off;
  if (e < OFF_PS)      { srcs = pa_s;          dsts = pa_d;          off = 0; }
  else if (e < OFF_AP) { srcs = ps_s - OFF_PS; dsts = ps_d - OFF_PS; off = ROW_PS; }
  else if (e < OFF_SP) { srcs = ap_s - OFF_AP; dsts = ap_d - OFF_AP; off = ROW_AP; }
  else                 { srcs = sp_s - OFF_SP; dsts = sp_d - OFF_SP; off = ROW_SP; }
  int4 s4 = *(const int4*)(srcs + e);
  int4 d4 = *(const int4*)(dsts + e);
  uint2 rr = *(const uint2*)(rank16 + e);
  ci[rp[off + d4.x] + (int)(rr.x & 0xffffu)] = s4.x;
  ci[rp[off + d4.y] + (int)(rr.x >> 16)]     = s4.y;
  ci[rp[off + d4.z] + (int)(rr.y & 0xffffu)] = s4.z;
  ci[rp[off + d4.w] + (int)(rr.y >> 16)]     = s4.w;
}

// K3: fill the pa|ps half only (feeds gather16)
__global__ __launch_bounds__(256) void fill_paps(
    const int* __restrict__ pa_s, const int* __restrict__ pa_d,
    const int* __restrict__ ps_s, const int* __restrict__ ps_d,
    const int* __restrict__ ap_s, const int* __restrict__ ap_d,
    const int* __restrict__ sp_s, const int* __restrict__ sp_d,
    const int* __restrict__ rp, const u16* __restrict__ rank16,
    int* __restrict__ ci)
{
  int e = blockIdx.x*1024 + threadIdx.x*4;
  if (e < OFF_AP)
    fill4(e, pa_s, pa_d, ps_s, ps_d, ap_s, ap_d, sp_s, sp_d, rp, rank16, ci);
}

// K4: gather16 (authors+subjects from yz) || fill of the ap|sp half.
// Disjoint ci ranges: gather reads slots < OFF_AP; fill writes slots >= OFF_AP.
__global__ __launch_bounds__(256) void g16_fill(
    const float* __restrict__ yz,
    const int* __restrict__ rp, const int* __restrict__ ci,
    float* __restrict__ m16,
    const int* __restrict__ pa_s, const int* __restrict__ pa_d,
    const int* __restrict__ ps_s, const int* __restrict__ ps_d,
    const int* __restrict__ ap_s, const int* __restrict__ ap_d,
    const int* __restrict__ sp_s, const int* __restrict__ sp_d,
    const u16* __restrict__ rank16, int* __restrict__ ci_w)
{
  const int b = blockIdx.x;
  if (b < NB_FILLB) {
    int e = OFF_AP + b*1024 + threadIdx.x*4;
    if (e < ETOT)
      fill4(e, pa_s, pa_d, ps_s, ps_d, ap_s, ap_d, sp_s, sp_d, rp, rank16, ci_w);
    return;
  }
  int t = (b - NB_FILLB)*256 + threadIdx.x;
  int row = t >> 4, lane = t & 15;
  if (row >= NA + NS) return;
  int beg = rp[row], end = rp[row+1];
  int off = (row < NA ? 0 : 16) + lane;
  float a = 0.f, bb = 0.f;
  int e = beg;
  for (; e + 1 < end; e += 2) {
    a  += yz[(size_t)ci[e]  *32 + off];
    bb += yz[(size_t)ci[e+1]*32 + off];
  }
  if (e < end) a += yz[(size_t)ci[e]*32 + off];
  int d = end - beg;
  m16[(size_t)row*16 + lane] = (a + bb) / (float)(d > 0 ? d : 1);
}

// K5: papers: out = mean_ap(m16_a) + mean_sp(m16_s) + out_b
__global__ __launch_bounds__(256) void gather2_16(
    const float* __restrict__ f1, const int* __restrict__ rp1,
    const float* __restrict__ f2, const int* __restrict__ rp2,
    const int* __restrict__ ci, const float* __restrict__ ob,
    float* __restrict__ O, int n)
{
  int t = blockIdx.x*256 + threadIdx.x;
  int row = t >> 4, lane = t & 15;
  if (row >= n) return;

  float s1 = 0.f, s1b = 0.f;
  {
    int beg = rp1[row], end = rp1[row+1];
    int e = beg;
    for (; e + 1 < end; e += 2) {
      s1  += f1[(size_t)ci[e]  *16 + lane];
      s1b += f1[(size_t)ci[e+1]*16 + lane];
    }
    if (e < end) s1 += f1[(size_t)ci[e]*16 + lane];
    int d = end - beg;
    s1 = (s1 + s1b) / (float)(d > 0 ? d : 1);
  }
  float s2 = 0.f, s2b = 0.f;
  {
    int beg = rp2[row], end = rp2[row+1];
    int e = beg;
    for (; e + 1 < end; e += 2) {
      s2  += f2[(size_t)ci[e]  *16 + lane];
      s2b += f2[(size_t)ci[e+1]*16 + lane];
    }
    if (e < end) s2 += f2[(size_t)ci[e]*16 + lane];
    int d = end - beg;
    s2 = (s2 + s2b) / (float)(d > 0 ? d : 1);
  }
  O[(size_t)row*16 + lane] = s1 + s2 + ob[lane];
}

extern "C" void kernel_launch(void* const* d_in, const int* in_sizes, int n_in,
                              void* d_out, int out_size, void* d_ws, size_t ws_size,
                              hipStream_t stream)
{
  const float* x_p = (const float*)d_in[0];
  const int* pa_src=(const int*)d_in[3]; const int* pa_dst=(const int*)d_in[4];
  const int* ap_src=(const int*)d_in[5]; const int* ap_dst=(const int*)d_in[6];
  const int* ps_src=(const int*)d_in[7]; const int* ps_dst=(const int*)d_in[8];
  const int* sp_src=(const int*)d_in[9]; const int* sp_dst=(const int*)d_in[10];
  const float* ewp=(const float*)d_in[11]; const float* ebp=(const float*)d_in[12];
  const float* w0_pa=(const float*)d_in[17];
  const float* w0_ps=(const float*)d_in[19];
  const float* w1_ap=(const float*)d_in[22];
  const float* w1_sp=(const float*)d_in[24];
  const float* out_w=(const float*)d_in[25]; const float* out_b=(const float*)d_in[26];
  float* out = (float*)d_out;

  // ---- workspace layout (~28 MB) ----
  char* wp = (char*)d_ws;
  auto alloc = [&](size_t bytes) { char* p = wp; wp += (bytes + 255) & ~(size_t)255; return p; };
  float* yz     = (float*)alloc((size_t)NP*32*4);         // 12.8 MB
  int*   ci     = (int*)alloc((size_t)ETOT*4);            // 6.4 MB
  float* m16    = (float*)alloc((size_t)(NA+NS)*16*4);    // 3.52 MB
  u16*   wpk    = (u16*)alloc((size_t)256*128*2);
  u16*   WFb    = (u16*)alloc((size_t)8*64*8*2);          // 8 KB bf16 B-frags
  int*   h      = (int*)alloc((size_t)NT*4);              // 1.02 MB (memset)
  u16*   rank16 = (u16*)alloc((size_t)ETOT*2);            // 3.2 MB
  int*   rpG    = (int*)alloc((size_t)(NT+1)*4);
  int*   part   = (int*)alloc((size_t)64*4);

  // ---- K0: fold + pack (tiny) ----
  hipMemsetAsync(h, 0, (size_t)NT*4, stream);
  fold_pack<<<NB_FOLD+NB_PACK,256,0,stream>>>(
      w0_pa, w1_ap, w0_ps, w1_sp, out_w, WFb, ewp, wpk);

  // ---- K1: histogram || encoder (independent; co-grid) ----
  hist_enc<<<NB_HIST+NB_ENC,256,0,stream>>>(
      pa_dst, ps_dst, ap_dst, sp_dst, h, rank16,
      x_p, wpk, ebp, WFb, yz);

  // ---- K2: scans -> rowptr ----
  int nch = (NT + 4095)/4096;   // 63
  scan_partial<<<nch,256,0,stream>>>(h, NT, part);
  scan_chunk  <<<nch,256,0,stream>>>(h, NT, part, rpG);

  // ---- K3: fill pa|ps half (feeds gather16) ----
  fill_paps<<<NB_FILLA,256,0,stream>>>(
      pa_src, pa_dst, ps_src, ps_dst, ap_src, ap_dst, sp_src, sp_dst,
      rpG, rank16, ci);

  // ---- K4: gather16 || fill ap|sp half (disjoint ci ranges) ----
  g16_fill<<<NB_FILLB+NB_G16,256,0,stream>>>(
      yz, rpG, ci, m16,
      pa_src, pa_dst, ps_src, ps_dst, ap_src, ap_dst, sp_src, sp_dst,
      rank16, ci);

  // ---- K5: final paper aggregation + bias -> d_out ----
  gather2_16<<<(((size_t)NP*16)+255)/256,256,0,stream>>>(
      m16, rpG + ROW_AP,
      m16 + (size_t)NA*16, rpG + ROW_SP,
      ci, out_b, out, NP);
}